// Round 4
// baseline (3087.391 us; speedup 1.0000x reference)
//
#include <hip/hip_runtime.h>

#define DIN 256
#define H   128
#define DOUT 64

#define EPI_RELU 0
#define EPI_BN   1
#define EPI_NONE 2

#define BKT_SHIFT 7                 // 128 nodes per bucket
#define BKT_NODES 128
#define BKT_CAP   4096              // slots per bucket (mean 2048, sigma ~45)

typedef __attribute__((ext_vector_type(8))) short bf16x8;
typedef __attribute__((ext_vector_type(4))) float f32x4;

__device__ inline unsigned short f2bf(float f) {
  union { float f; unsigned u; } v; v.f = f;
  unsigned u = v.u;
  u += 0x7FFFu + ((u >> 16) & 1u);   // round-to-nearest-even
  return (unsigned short)(u >> 16);
}
__device__ inline float bf2f(unsigned u16) {
  union { unsigned u; float f; } v; v.u = u16 << 16;
  return v.f;
}

// ---------------- bucketed edge fill ----------------
// Groups edges by dst>>7 into fixed-capacity buckets. Packed record:
// src (17 bits) | dst_local (7 bits) << 17.  One global atomic per
// (block, bucket) chunk reservation; chunk writes are temporally local.
#define FILL_TPB 1024
#define FILL_EPT 16
#define FILL_EPB (FILL_TPB * FILL_EPT)

__global__ __launch_bounds__(FILL_TPB) void bucket_fill(
    const int* __restrict__ src, const int* __restrict__ dst,
    int* __restrict__ bcur, unsigned* __restrict__ bedges,
    int nbkt, int e) {
  __shared__ int hist[1024];        // >= nbkt (782)
  int tid = threadIdx.x;
  int base = blockIdx.x * FILL_EPB;
  for (int i = tid; i < nbkt; i += FILL_TPB) hist[i] = 0;
  __syncthreads();

  int  es[FILL_EPT], ed[FILL_EPT];
#pragma unroll
  for (int j = 0; j < FILL_EPT; ++j) {
    int i = base + j * FILL_TPB + tid;
    if (i < e) {
      es[j] = src[i];
      ed[j] = dst[i];
      atomicAdd(&hist[ed[j] >> BKT_SHIFT], 1);
    } else {
      es[j] = -1; ed[j] = 0;
    }
  }
  __syncthreads();
  // reserve global chunks; hist[b] becomes the absolute cursor
  for (int b = tid; b < nbkt; b += FILL_TPB) {
    int cnt = hist[b];
    hist[b] = cnt ? atomicAdd(&bcur[b], cnt) : 0;
  }
  __syncthreads();
#pragma unroll
  for (int j = 0; j < FILL_EPT; ++j) {
    if (es[j] >= 0) {
      int b = ed[j] >> BKT_SHIFT;
      int p = atomicAdd(&hist[b], 1);
      if (p < BKT_CAP)
        bedges[(size_t)b * BKT_CAP + p] =
            (unsigned)es[j] | ((unsigned)(ed[j] & (BKT_NODES - 1)) << 17);
    }
  }
}

// ---------------- bucketed mean aggregation ----------------
// One block per bucket: 64KB fp32 LDS accumulator for 128 nodes x 128 feats,
// ds_add_f32 scatter (no-return -> dependency-free gather loop), LDS degree
// count, then coalesced bf16 write-out.
__global__ __launch_bounds__(256) void agg_bucketed(
    const unsigned* __restrict__ h, const int* __restrict__ bcur,
    const unsigned* __restrict__ bedges, unsigned* __restrict__ mean, int n) {
  __shared__ float acc[BKT_NODES * H];
  __shared__ int degs[BKT_NODES];
  int tid = threadIdx.x, lane = tid & 63, wave = tid >> 6;
  int b = blockIdx.x;
  for (int i = tid; i < BKT_NODES * H; i += 256) acc[i] = 0.f;
  if (tid < BKT_NODES) degs[tid] = 0;
  __syncthreads();

  int cnt = bcur[b];
  if (cnt > BKT_CAP) cnt = BKT_CAP;
  const unsigned* eb = bedges + (size_t)b * BKT_CAP;

  for (int e0 = wave * 64; e0 < cnt; e0 += 256) {
    int m = cnt - e0; if (m > 64) m = 64;
    unsigned ev = eb[e0 + (lane < m ? lane : m - 1)];
    int j = 0;
    for (; j + 4 <= m; j += 4) {
      unsigned e0w = __shfl(ev, j), e1w = __shfl(ev, j + 1);
      unsigned e2w = __shfl(ev, j + 2), e3w = __shfl(ev, j + 3);
      unsigned v0 = h[(size_t)(e0w & 0x1FFFF) * (H / 2) + lane];
      unsigned v1 = h[(size_t)(e1w & 0x1FFFF) * (H / 2) + lane];
      unsigned v2 = h[(size_t)(e2w & 0x1FFFF) * (H / 2) + lane];
      unsigned v3 = h[(size_t)(e3w & 0x1FFFF) * (H / 2) + lane];
      int d0 = (e0w >> 17) & 127, d1 = (e1w >> 17) & 127;
      int d2 = (e2w >> 17) & 127, d3 = (e3w >> 17) & 127;
      atomicAdd(&acc[d0 * H + 2 * lane],     bf2f(v0 & 0xffffu));
      atomicAdd(&acc[d0 * H + 2 * lane + 1], bf2f(v0 >> 16));
      atomicAdd(&acc[d1 * H + 2 * lane],     bf2f(v1 & 0xffffu));
      atomicAdd(&acc[d1 * H + 2 * lane + 1], bf2f(v1 >> 16));
      atomicAdd(&acc[d2 * H + 2 * lane],     bf2f(v2 & 0xffffu));
      atomicAdd(&acc[d2 * H + 2 * lane + 1], bf2f(v2 >> 16));
      atomicAdd(&acc[d3 * H + 2 * lane],     bf2f(v3 & 0xffffu));
      atomicAdd(&acc[d3 * H + 2 * lane + 1], bf2f(v3 >> 16));
      if (lane == 0) {
        atomicAdd(&degs[d0], 1); atomicAdd(&degs[d1], 1);
        atomicAdd(&degs[d2], 1); atomicAdd(&degs[d3], 1);
      }
    }
    for (; j < m; ++j) {
      unsigned ew = __shfl(ev, j);
      unsigned v = h[(size_t)(ew & 0x1FFFF) * (H / 2) + lane];
      int dl = (ew >> 17) & 127;
      atomicAdd(&acc[dl * H + 2 * lane],     bf2f(v & 0xffffu));
      atomicAdd(&acc[dl * H + 2 * lane + 1], bf2f(v >> 16));
      if (lane == 0) atomicAdd(&degs[dl], 1);
    }
  }
  __syncthreads();

  int row0 = b * BKT_NODES;
  for (int i = tid; i < BKT_NODES * (H / 2); i += 256) {
    int nl = i >> 6, c = i & 63;
    int row = row0 + nl;
    if (row < n) {
      int d = degs[nl];
      float invd = 1.f / (float)(d > 0 ? d : 1);
      float a0 = acc[nl * H + 2 * c] * invd;
      float a1 = acc[nl * H + 2 * c + 1] * invd;
      mean[(size_t)row * (H / 2) + c] =
          (unsigned)f2bf(a0) | ((unsigned)f2bf(a1) << 16);
    }
  }
}

// ---------------- weight preconvert: Wt[m][k] = bf16(W[k][m]) ----------------
__global__ __launch_bounds__(256) void prep_w(
    const float* __restrict__ w_in, const float* __restrict__ w_l1,
    const float* __restrict__ w_r1, const float* __restrict__ w_l2,
    const float* __restrict__ w_r2, const float* __restrict__ w_out,
    unsigned short* __restrict__ t_in, unsigned short* __restrict__ t_l1,
    unsigned short* __restrict__ t_r1, unsigned short* __restrict__ t_l2,
    unsigned short* __restrict__ t_r2, unsigned short* __restrict__ t_out) {
  int i = blockIdx.x * 256 + threadIdx.x;
  const float* s; unsigned short* d; int K, M, off;
  if (i < 32768)       { s = w_in;  d = t_in;  K = 256; M = 128; off = i; }
  else if (i < 49152)  { s = w_l1;  d = t_l1;  K = 128; M = 128; off = i - 32768; }
  else if (i < 65536)  { s = w_r1;  d = t_r1;  K = 128; M = 128; off = i - 49152; }
  else if (i < 81920)  { s = w_l2;  d = t_l2;  K = 128; M = 128; off = i - 65536; }
  else if (i < 98304)  { s = w_r2;  d = t_r2;  K = 128; M = 128; off = i - 81920; }
  else if (i < 106496) { s = w_out; d = t_out; K = 128; M = 64;  off = i - 98304; }
  else return;
  int m = off / K, k = off % K;
  d[off] = f2bf(s[(size_t)k * M + m]);
}

// ---------------- bf16 MFMA GEMM, barrier-free k-loop ----------------
template <int NPH, int KOFF2, int AK, int M, int EPI, bool AFP32, bool OUTF32>
__global__ __launch_bounds__(256) void gemm_mfma(
    const void* __restrict__ A1, const void* __restrict__ A2,
    const unsigned short* __restrict__ W1, const unsigned short* __restrict__ W2,
    const float* __restrict__ bias, const float* __restrict__ gamma,
    const float* __restrict__ beta, void* __restrict__ Cv, int n) {
  constexpr int KP = 136;            // 128 + 8 pad
  constexpr int NT = M / 16;
  __shared__ __align__(16) unsigned short Bs[M * KP];

  int tid = threadIdx.x, lane = tid & 63, wave = tid >> 6;
  int m16 = lane & 15, quad = lane >> 4;
  int row0 = blockIdx.x * 128;

  f32x4 acc[2][NT];
#pragma unroll
  for (int rt = 0; rt < 2; ++rt)
#pragma unroll
    for (int t = 0; t < NT; ++t) acc[rt][t] = (f32x4){0.f, 0.f, 0.f, 0.f};

  int rowa[2];
#pragma unroll
  for (int rt = 0; rt < 2; ++rt) {
    int r = row0 + wave * 32 + rt * 16 + m16;
    rowa[rt] = (r < n) ? r : (n - 1);
  }

#pragma unroll
  for (int ph = 0; ph < NPH; ++ph) {
    const void* A = ph ? A2 : A1;
    const unsigned short* W = ph ? W2 : W1;
    const int koff = ph ? KOFF2 : 0;
    if (ph) __syncthreads();
    for (int i = tid; i < M * 16; i += 256) {
      int r = i >> 4, c = i & 15;
      *(uint4*)&Bs[r * KP + c * 8] = *(const uint4*)&W[(size_t)r * AK + koff + c * 8];
    }
    __syncthreads();
#pragma unroll
    for (int kt = 0; kt < 128; kt += 32) {
      bf16x8 af[2];
#pragma unroll
      for (int rt = 0; rt < 2; ++rt) {
        if constexpr (AFP32) {
          const float* ap = (const float*)A + (size_t)rowa[rt] * AK + koff + kt + quad * 8;
          float4 v0 = *(const float4*)ap;
          float4 v1 = *(const float4*)(ap + 4);
          union { bf16x8 v; unsigned u[4]; } p;
          p.u[0] = (unsigned)f2bf(v0.x) | ((unsigned)f2bf(v0.y) << 16);
          p.u[1] = (unsigned)f2bf(v0.z) | ((unsigned)f2bf(v0.w) << 16);
          p.u[2] = (unsigned)f2bf(v1.x) | ((unsigned)f2bf(v1.y) << 16);
          p.u[3] = (unsigned)f2bf(v1.z) | ((unsigned)f2bf(v1.w) << 16);
          af[rt] = p.v;
        } else {
          af[rt] = *(const bf16x8*)((const unsigned short*)A +
                                    (size_t)rowa[rt] * AK + koff + kt + quad * 8);
        }
      }
#pragma unroll
      for (int t = 0; t < NT; ++t) {
        bf16x8 bfr = *(const bf16x8*)&Bs[(t * 16 + m16) * KP + kt + quad * 8];
        acc[0][t] = __builtin_amdgcn_mfma_f32_16x16x32_bf16(af[0], bfr, acc[0][t], 0, 0, 0);
        acc[1][t] = __builtin_amdgcn_mfma_f32_16x16x32_bf16(af[1], bfr, acc[1][t], 0, 0, 0);
      }
    }
  }

  const float inv_std = rsqrtf(1.f + 1e-5f);
#pragma unroll
  for (int t = 0; t < NT; ++t) {
    int col = t * 16 + m16;
    float bv = bias[col];
    float sc = 1.f, bt2 = 0.f;
    if constexpr (EPI == EPI_BN) {
      sc = gamma[col] * inv_std;
      bt2 = beta[col];
    }
#pragma unroll
    for (int rt = 0; rt < 2; ++rt) {
#pragma unroll
      for (int r = 0; r < 4; ++r) {
        int row = row0 + wave * 32 + rt * 16 + quad * 4 + r;
        if (row < n) {
          float v = acc[rt][t][r] + bv;
          if constexpr (EPI == EPI_BN) v = fmaxf(v * sc + bt2, 0.f);
          else if constexpr (EPI == EPI_RELU) v = fmaxf(v, 0.f);
          if constexpr (OUTF32)
            ((float*)Cv)[(size_t)row * M + col] = v;
          else
            ((unsigned short*)Cv)[(size_t)row * M + col] = f2bf(v);
        }
      }
    }
  }
}

extern "C" void kernel_launch(void* const* d_in, const int* in_sizes, int n_in,
                              void* d_out, int out_size, void* d_ws, size_t ws_size,
                              hipStream_t stream) {
  const float* x     = (const float*)d_in[0];
  const int*   ei    = (const int*)d_in[1];
  const float* w_in  = (const float*)d_in[2];
  const float* b_in  = (const float*)d_in[3];
  const float* w_l1  = (const float*)d_in[4];
  const float* b_l1  = (const float*)d_in[5];
  const float* w_r1  = (const float*)d_in[6];
  const float* g1    = (const float*)d_in[7];
  const float* be1   = (const float*)d_in[8];
  const float* w_l2  = (const float*)d_in[9];
  const float* b_l2  = (const float*)d_in[10];
  const float* w_r2  = (const float*)d_in[11];
  const float* g2    = (const float*)d_in[12];
  const float* be2   = (const float*)d_in[13];
  const float* w_out = (const float*)d_in[14];
  const float* b_out = (const float*)d_in[15];
  float* out = (float*)d_out;

  int N = in_sizes[0] / DIN;
  int E = in_sizes[1] / 2;
  const int* src = ei;       // edge_index[0]
  const int* dst = ei + E;   // edge_index[1]
  int nbkt = (N + BKT_NODES - 1) / BKT_NODES;   // 782

  char* ws = (char*)d_ws;
  size_t off = 0;
  auto alloc = [&](size_t bytes) -> char* {
    char* p = ws + off;
    off += (bytes + 255) & ~(size_t)255;
    return p;
  };
  unsigned short* buf0 = (unsigned short*)alloc((size_t)N * H * 2);  // h0 -> mean2
  unsigned short* buf1 = (unsigned short*)alloc((size_t)N * H * 2);  // mean1 -> h2
  unsigned short* buf2 = (unsigned short*)alloc((size_t)N * H * 2);  // h1
  int* bcur        = (int*)alloc((size_t)nbkt * 4);
  unsigned* bedges = (unsigned*)alloc((size_t)nbkt * BKT_CAP * 4);
  unsigned short* t_in  = (unsigned short*)alloc(32768 * 2);
  unsigned short* t_l1  = (unsigned short*)alloc(16384 * 2);
  unsigned short* t_r1  = (unsigned short*)alloc(16384 * 2);
  unsigned short* t_l2  = (unsigned short*)alloc(16384 * 2);
  unsigned short* t_r2  = (unsigned short*)alloc(16384 * 2);
  unsigned short* t_out = (unsigned short*)alloc(8192 * 2);
  (void)ws_size;

  // ---- bucket edges + weight prep ----
  hipMemsetAsync(bcur, 0, (size_t)nbkt * 4, stream);
  bucket_fill<<<(E + FILL_EPB - 1) / FILL_EPB, FILL_TPB, 0, stream>>>(
      src, dst, bcur, bedges, nbkt, E);
  prep_w<<<(106496 + 255) / 256, 256, 0, stream>>>(
      w_in, w_l1, w_r1, w_l2, w_r2, w_out, t_in, t_l1, t_r1, t_l2, t_r2, t_out);

  int gblocks = (N + 127) / 128;

  // h0 = relu(x @ w_in + b_in)
  gemm_mfma<2, 128, 256, 128, EPI_RELU, true, false><<<gblocks, 256, 0, stream>>>(
      x, x, t_in, t_in, b_in, nullptr, nullptr, buf0, N);
  // mean1
  agg_bucketed<<<nbkt, 256, 0, stream>>>((const unsigned*)buf0, bcur, bedges,
                                         (unsigned*)buf1, N);
  // h1 = relu(bn(mean1@w_l1 + h0@w_r1 + b_l1))
  gemm_mfma<2, 0, 128, 128, EPI_BN, false, false><<<gblocks, 256, 0, stream>>>(
      buf1, buf0, t_l1, t_r1, b_l1, g1, be1, buf2, N);
  // mean2
  agg_bucketed<<<nbkt, 256, 0, stream>>>((const unsigned*)buf2, bcur, bedges,
                                         (unsigned*)buf0, N);
  // h2 = relu(bn(mean2@w_l2 + h1@w_r2 + b_l2))
  gemm_mfma<2, 0, 128, 128, EPI_BN, false, false><<<gblocks, 256, 0, stream>>>(
      buf0, buf2, t_l2, t_r2, b_l2, g2, be2, buf1, N);
  // out = h2 @ w_out + b_out
  gemm_mfma<1, 0, 128, 64, EPI_NONE, false, true><<<gblocks, 256, 0, stream>>>(
      buf1, buf1, t_out, t_out, b_out, nullptr, nullptr, out, N);
}

// Round 5
// 479.871 us; speedup vs baseline: 6.4338x; 6.4338x over previous
//
#include <hip/hip_runtime.h>

#define DIN 256
#define H   128
#define DOUT 64

#define EPI_RELU 0
#define EPI_BN   1
#define EPI_NONE 2

#define BKT_SHIFT 7                 // 128 nodes per bucket
#define BKT_NODES 128
#define BKT_CAP   4096              // slots per bucket (mean 2048, sigma ~45)

typedef __attribute__((ext_vector_type(8))) short bf16x8;
typedef __attribute__((ext_vector_type(4))) float f32x4;

__device__ inline unsigned short f2bf(float f) {
  union { float f; unsigned u; } v; v.f = f;
  unsigned u = v.u;
  u += 0x7FFFu + ((u >> 16) & 1u);   // round-to-nearest-even
  return (unsigned short)(u >> 16);
}
__device__ inline float bf2f(unsigned u16) {
  union { unsigned u; float f; } v; v.u = u16 << 16;
  return v.f;
}

// ---------------- stage 1: bucket edges by dst>>7 ----------------
// Packed record: src (17 bits) | dst_local (7 bits) << 17.
#define FILL_TPB 1024
#define FILL_EPT 16
#define FILL_EPB (FILL_TPB * FILL_EPT)

__global__ __launch_bounds__(FILL_TPB) void bucket_fill(
    const int* __restrict__ src, const int* __restrict__ dst,
    int* __restrict__ bcur, unsigned* __restrict__ bedges,
    int nbkt, int e) {
  __shared__ int hist[1024];        // >= nbkt (782)
  int tid = threadIdx.x;
  int base = blockIdx.x * FILL_EPB;
  for (int i = tid; i < nbkt; i += FILL_TPB) hist[i] = 0;
  __syncthreads();

  int es[FILL_EPT], ed[FILL_EPT];
#pragma unroll
  for (int j = 0; j < FILL_EPT; ++j) {
    int i = base + j * FILL_TPB + tid;
    if (i < e) {
      es[j] = src[i];
      ed[j] = dst[i];
      atomicAdd(&hist[ed[j] >> BKT_SHIFT], 1);
    } else {
      es[j] = -1; ed[j] = 0;
    }
  }
  __syncthreads();
  for (int b = tid; b < nbkt; b += FILL_TPB) {
    int cnt = hist[b];
    hist[b] = cnt ? atomicAdd(&bcur[b], cnt) : 0;
  }
  __syncthreads();
#pragma unroll
  for (int j = 0; j < FILL_EPT; ++j) {
    if (es[j] >= 0) {
      int b = ed[j] >> BKT_SHIFT;
      int p = atomicAdd(&hist[b], 1);
      if (p < BKT_CAP)
        bedges[(size_t)b * BKT_CAP + p] =
            (unsigned)es[j] | ((unsigned)(ed[j] & (BKT_NODES - 1)) << 17);
    }
  }
}

// ---------------- stage 2: in-LDS counting sort per bucket -> CSR ----------------
__global__ __launch_bounds__(256) void bucket_sort(
    const int* __restrict__ bcur, const unsigned* __restrict__ bedges,
    int* __restrict__ csr, int* __restrict__ row_beg, int* __restrict__ deg,
    int n) {
  __shared__ unsigned rec[BKT_CAP];
  __shared__ int srcs[BKT_CAP];
  __shared__ int hist[BKT_NODES];
  __shared__ int cursor[BKT_NODES];
  int tid = threadIdx.x;
  int b = blockIdx.x;
  int cnt = bcur[b];
  if (cnt > BKT_CAP) cnt = BKT_CAP;
  const unsigned* eb = bedges + (size_t)b * BKT_CAP;

  if (tid < BKT_NODES) hist[tid] = 0;
  __syncthreads();
  for (int i = tid; i < cnt; i += 256) {
    unsigned r = eb[i];
    rec[i] = r;
    atomicAdd(&hist[(r >> 17) & 127], 1);
  }
  __syncthreads();
  // inclusive scan over 128 bins (Hillis-Steele)
  int myc = (tid < BKT_NODES) ? hist[tid] : 0;
#pragma unroll
  for (int off = 1; off < BKT_NODES; off <<= 1) {
    int v = 0;
    if (tid < BKT_NODES && tid >= off) v = hist[tid - off];
    __syncthreads();
    if (tid < BKT_NODES) hist[tid] += v;
    __syncthreads();
  }
  if (tid < BKT_NODES) {
    int start = hist[tid] - myc;
    cursor[tid] = start;
    int node = b * BKT_NODES + tid;
    if (node < n) {
      row_beg[node] = b * BKT_CAP + start;
      deg[node] = myc;
    }
  }
  __syncthreads();
  for (int i = tid; i < cnt; i += 256) {
    unsigned r = rec[i];
    int p = atomicAdd(&cursor[(r >> 17) & 127], 1);
    srcs[p] = (int)(r & 0x1FFFFu);
  }
  __syncthreads();
  for (int i = tid; i < cnt; i += 256)
    csr[(size_t)b * BKT_CAP + i] = srcs[i];
}

// ---------------- mean aggregation: one wave per node, unrolled gather ----------------
__global__ __launch_bounds__(256) void agg_kernel(const unsigned* __restrict__ h,
                                                  const int* __restrict__ row_beg,
                                                  const int* __restrict__ deg,
                                                  const int* __restrict__ csr,
                                                  unsigned* __restrict__ mean, int n) {
  int node = (int)((blockIdx.x * blockDim.x + threadIdx.x) >> 6);
  if (node >= n) return;
  int lane = threadIdx.x & 63;
  int beg = row_beg[node], d = deg[node];
  float ax = 0.f, ay = 0.f;
  for (int j0 = 0; j0 < d; j0 += 64) {
    int cnt = min(64, d - j0);
    int li = j0 + (lane < cnt ? lane : cnt - 1);
    int sv = csr[beg + li];
    int j = 0;
    for (; j + 4 <= cnt; j += 4) {
      int s0 = __shfl(sv, j);
      int s1 = __shfl(sv, j + 1);
      int s2 = __shfl(sv, j + 2);
      int s3 = __shfl(sv, j + 3);
      unsigned v0 = h[(size_t)s0 * (H / 2) + lane];
      unsigned v1 = h[(size_t)s1 * (H / 2) + lane];
      unsigned v2 = h[(size_t)s2 * (H / 2) + lane];
      unsigned v3 = h[(size_t)s3 * (H / 2) + lane];
      ax += bf2f(v0 & 0xffffu) + bf2f(v1 & 0xffffu) +
            bf2f(v2 & 0xffffu) + bf2f(v3 & 0xffffu);
      ay += bf2f(v0 >> 16) + bf2f(v1 >> 16) + bf2f(v2 >> 16) + bf2f(v3 >> 16);
    }
    for (; j < cnt; ++j) {
      int s = __shfl(sv, j);
      unsigned v = h[(size_t)s * (H / 2) + lane];
      ax += bf2f(v & 0xffffu);
      ay += bf2f(v >> 16);
    }
  }
  float invd = 1.f / (float)(d > 0 ? d : 1);
  mean[(size_t)node * (H / 2) + lane] =
      (unsigned)f2bf(ax * invd) | ((unsigned)f2bf(ay * invd) << 16);
}

// ---------------- weight preconvert: Wt[m][k] = bf16(W[k][m]) ----------------
__global__ __launch_bounds__(256) void prep_w(
    const float* __restrict__ w_in, const float* __restrict__ w_l1,
    const float* __restrict__ w_r1, const float* __restrict__ w_l2,
    const float* __restrict__ w_r2, const float* __restrict__ w_out,
    unsigned short* __restrict__ t_in, unsigned short* __restrict__ t_l1,
    unsigned short* __restrict__ t_r1, unsigned short* __restrict__ t_l2,
    unsigned short* __restrict__ t_r2, unsigned short* __restrict__ t_out) {
  int i = blockIdx.x * 256 + threadIdx.x;
  const float* s; unsigned short* d; int K, M, off;
  if (i < 32768)       { s = w_in;  d = t_in;  K = 256; M = 128; off = i; }
  else if (i < 49152)  { s = w_l1;  d = t_l1;  K = 128; M = 128; off = i - 32768; }
  else if (i < 65536)  { s = w_r1;  d = t_r1;  K = 128; M = 128; off = i - 49152; }
  else if (i < 81920)  { s = w_l2;  d = t_l2;  K = 128; M = 128; off = i - 65536; }
  else if (i < 98304)  { s = w_r2;  d = t_r2;  K = 128; M = 128; off = i - 81920; }
  else if (i < 106496) { s = w_out; d = t_out; K = 128; M = 64;  off = i - 98304; }
  else return;
  int m = off / K, k = off % K;
  d[off] = f2bf(s[(size_t)k * M + m]);
}

// ---------------- bf16 MFMA GEMM, barrier-free k-loop ----------------
template <int NPH, int KOFF2, int AK, int M, int EPI, bool AFP32, bool OUTF32>
__global__ __launch_bounds__(256) void gemm_mfma(
    const void* __restrict__ A1, const void* __restrict__ A2,
    const unsigned short* __restrict__ W1, const unsigned short* __restrict__ W2,
    const float* __restrict__ bias, const float* __restrict__ gamma,
    const float* __restrict__ beta, void* __restrict__ Cv, int n) {
  constexpr int KP = 136;            // 128 + 8 pad
  constexpr int NT = M / 16;
  __shared__ __align__(16) unsigned short Bs[M * KP];

  int tid = threadIdx.x, lane = tid & 63, wave = tid >> 6;
  int m16 = lane & 15, quad = lane >> 4;
  int row0 = blockIdx.x * 128;

  f32x4 acc[2][NT];
#pragma unroll
  for (int rt = 0; rt < 2; ++rt)
#pragma unroll
    for (int t = 0; t < NT; ++t) acc[rt][t] = (f32x4){0.f, 0.f, 0.f, 0.f};

  int rowa[2];
#pragma unroll
  for (int rt = 0; rt < 2; ++rt) {
    int r = row0 + wave * 32 + rt * 16 + m16;
    rowa[rt] = (r < n) ? r : (n - 1);
  }

#pragma unroll
  for (int ph = 0; ph < NPH; ++ph) {
    const void* A = ph ? A2 : A1;
    const unsigned short* W = ph ? W2 : W1;
    const int koff = ph ? KOFF2 : 0;
    if (ph) __syncthreads();
    for (int i = tid; i < M * 16; i += 256) {
      int r = i >> 4, c = i & 15;
      *(uint4*)&Bs[r * KP + c * 8] = *(const uint4*)&W[(size_t)r * AK + koff + c * 8];
    }
    __syncthreads();
#pragma unroll
    for (int kt = 0; kt < 128; kt += 32) {
      bf16x8 af[2];
#pragma unroll
      for (int rt = 0; rt < 2; ++rt) {
        if constexpr (AFP32) {
          const float* ap = (const float*)A + (size_t)rowa[rt] * AK + koff + kt + quad * 8;
          float4 v0 = *(const float4*)ap;
          float4 v1 = *(const float4*)(ap + 4);
          union { bf16x8 v; unsigned u[4]; } p;
          p.u[0] = (unsigned)f2bf(v0.x) | ((unsigned)f2bf(v0.y) << 16);
          p.u[1] = (unsigned)f2bf(v0.z) | ((unsigned)f2bf(v0.w) << 16);
          p.u[2] = (unsigned)f2bf(v1.x) | ((unsigned)f2bf(v1.y) << 16);
          p.u[3] = (unsigned)f2bf(v1.z) | ((unsigned)f2bf(v1.w) << 16);
          af[rt] = p.v;
        } else {
          af[rt] = *(const bf16x8*)((const unsigned short*)A +
                                    (size_t)rowa[rt] * AK + koff + kt + quad * 8);
        }
      }
#pragma unroll
      for (int t = 0; t < NT; ++t) {
        bf16x8 bfr = *(const bf16x8*)&Bs[(t * 16 + m16) * KP + kt + quad * 8];
        acc[0][t] = __builtin_amdgcn_mfma_f32_16x16x32_bf16(af[0], bfr, acc[0][t], 0, 0, 0);
        acc[1][t] = __builtin_amdgcn_mfma_f32_16x16x32_bf16(af[1], bfr, acc[1][t], 0, 0, 0);
      }
    }
  }

  const float inv_std = rsqrtf(1.f + 1e-5f);
#pragma unroll
  for (int t = 0; t < NT; ++t) {
    int col = t * 16 + m16;
    float bv = bias[col];
    float sc = 1.f, bt2 = 0.f;
    if constexpr (EPI == EPI_BN) {
      sc = gamma[col] * inv_std;
      bt2 = beta[col];
    }
#pragma unroll
    for (int rt = 0; rt < 2; ++rt) {
#pragma unroll
      for (int r = 0; r < 4; ++r) {
        int row = row0 + wave * 32 + rt * 16 + quad * 4 + r;
        if (row < n) {
          float v = acc[rt][t][r] + bv;
          if constexpr (EPI == EPI_BN) v = fmaxf(v * sc + bt2, 0.f);
          else if constexpr (EPI == EPI_RELU) v = fmaxf(v, 0.f);
          if constexpr (OUTF32)
            ((float*)Cv)[(size_t)row * M + col] = v;
          else
            ((unsigned short*)Cv)[(size_t)row * M + col] = f2bf(v);
        }
      }
    }
  }
}

extern "C" void kernel_launch(void* const* d_in, const int* in_sizes, int n_in,
                              void* d_out, int out_size, void* d_ws, size_t ws_size,
                              hipStream_t stream) {
  const float* x     = (const float*)d_in[0];
  const int*   ei    = (const int*)d_in[1];
  const float* w_in  = (const float*)d_in[2];
  const float* b_in  = (const float*)d_in[3];
  const float* w_l1  = (const float*)d_in[4];
  const float* b_l1  = (const float*)d_in[5];
  const float* w_r1  = (const float*)d_in[6];
  const float* g1    = (const float*)d_in[7];
  const float* be1   = (const float*)d_in[8];
  const float* w_l2  = (const float*)d_in[9];
  const float* b_l2  = (const float*)d_in[10];
  const float* w_r2  = (const float*)d_in[11];
  const float* g2    = (const float*)d_in[12];
  const float* be2   = (const float*)d_in[13];
  const float* w_out = (const float*)d_in[14];
  const float* b_out = (const float*)d_in[15];
  float* out = (float*)d_out;

  int N = in_sizes[0] / DIN;
  int E = in_sizes[1] / 2;
  const int* src = ei;       // edge_index[0]
  const int* dst = ei + E;   // edge_index[1]
  int nbkt = (N + BKT_NODES - 1) / BKT_NODES;   // 782

  char* ws = (char*)d_ws;
  size_t off = 0;
  auto alloc = [&](size_t bytes) -> char* {
    char* p = ws + off;
    off += (bytes + 255) & ~(size_t)255;
    return p;
  };
  unsigned short* buf0 = (unsigned short*)alloc((size_t)N * H * 2);  // h0 -> mean2
  unsigned short* buf1 = (unsigned short*)alloc((size_t)N * H * 2);  // mean1 -> h2
  unsigned short* buf2 = (unsigned short*)alloc((size_t)N * H * 2);  // h1
  int* bcur        = (int*)alloc((size_t)nbkt * 4);
  unsigned* bedges = (unsigned*)alloc((size_t)nbkt * BKT_CAP * 4);
  int* csr         = (int*)alloc((size_t)nbkt * BKT_CAP * 4);
  int* row_beg     = (int*)alloc((size_t)N * 4);
  int* deg         = (int*)alloc((size_t)N * 4);
  unsigned short* t_in  = (unsigned short*)alloc(32768 * 2);
  unsigned short* t_l1  = (unsigned short*)alloc(16384 * 2);
  unsigned short* t_r1  = (unsigned short*)alloc(16384 * 2);
  unsigned short* t_l2  = (unsigned short*)alloc(16384 * 2);
  unsigned short* t_r2  = (unsigned short*)alloc(16384 * 2);
  unsigned short* t_out = (unsigned short*)alloc(8192 * 2);
  (void)ws_size;

  // ---- CSR build: bucket -> in-LDS counting sort ----
  hipMemsetAsync(bcur, 0, (size_t)nbkt * 4, stream);
  bucket_fill<<<(E + FILL_EPB - 1) / FILL_EPB, FILL_TPB, 0, stream>>>(
      src, dst, bcur, bedges, nbkt, E);
  bucket_sort<<<nbkt, 256, 0, stream>>>(bcur, bedges, csr, row_beg, deg, N);
  prep_w<<<(106496 + 255) / 256, 256, 0, stream>>>(
      w_in, w_l1, w_r1, w_l2, w_r2, w_out, t_in, t_l1, t_r1, t_l2, t_r2, t_out);

  int gblocks = (N + 127) / 128;
  int ablocks = (N + 3) / 4;

  // h0 = relu(x @ w_in + b_in)
  gemm_mfma<2, 128, 256, 128, EPI_RELU, true, false><<<gblocks, 256, 0, stream>>>(
      x, x, t_in, t_in, b_in, nullptr, nullptr, buf0, N);
  // mean1
  agg_kernel<<<ablocks, 256, 0, stream>>>((const unsigned*)buf0, row_beg, deg,
                                          csr, (unsigned*)buf1, N);
  // h1 = relu(bn(mean1@w_l1 + h0@w_r1 + b_l1))
  gemm_mfma<2, 0, 128, 128, EPI_BN, false, false><<<gblocks, 256, 0, stream>>>(
      buf1, buf0, t_l1, t_r1, b_l1, g1, be1, buf2, N);
  // mean2
  agg_kernel<<<ablocks, 256, 0, stream>>>((const unsigned*)buf2, row_beg, deg,
                                          csr, (unsigned*)buf0, N);
  // h2 = relu(bn(mean2@w_l2 + h1@w_r2 + b_l2))
  gemm_mfma<2, 0, 128, 128, EPI_BN, false, false><<<gblocks, 256, 0, stream>>>(
      buf0, buf2, t_l2, t_r2, b_l2, g2, be2, buf1, N);
  // out = h2 @ w_out + b_out
  gemm_mfma<1, 0, 128, 64, EPI_NONE, false, true><<<gblocks, 256, 0, stream>>>(
      buf1, buf1, t_out, t_out, b_out, nullptr, nullptr, out, N);
}

// Round 6
// 466.348 us; speedup vs baseline: 6.6204x; 1.0290x over previous
//
#include <hip/hip_runtime.h>

#define DIN 256
#define H   128
#define DOUT 64

#define EPI_RELU 0
#define EPI_BN   1
#define EPI_NONE 2

#define BKT_SHIFT 7                 // 128 nodes per bucket
#define BKT_NODES 128
#define BKT_CAP   4096              // slots per bucket (mean 2048, sigma ~45)

typedef __attribute__((ext_vector_type(8))) short bf16x8;
typedef __attribute__((ext_vector_type(4))) float f32x4;

__device__ inline unsigned short f2bf(float f) {
  union { float f; unsigned u; } v; v.f = f;
  unsigned u = v.u;
  u += 0x7FFFu + ((u >> 16) & 1u);   // round-to-nearest-even
  return (unsigned short)(u >> 16);
}
__device__ inline float bf2f(unsigned u16) {
  union { unsigned u; float f; } v; v.u = u16 << 16;
  return v.f;
}

// ---------------- stage 1: bucket edges by dst>>7 ----------------
#define FILL_TPB 1024
#define FILL_EPT 16
#define FILL_EPB (FILL_TPB * FILL_EPT)

__global__ __launch_bounds__(FILL_TPB) void bucket_fill(
    const int* __restrict__ src, const int* __restrict__ dst,
    int* __restrict__ bcur, unsigned* __restrict__ bedges,
    int nbkt, int e) {
  __shared__ int hist[1024];        // >= nbkt (782)
  int tid = threadIdx.x;
  int base = blockIdx.x * FILL_EPB;
  for (int i = tid; i < nbkt; i += FILL_TPB) hist[i] = 0;
  __syncthreads();

  int es[FILL_EPT], ed[FILL_EPT];
#pragma unroll
  for (int j = 0; j < FILL_EPT; ++j) {
    int i = base + j * FILL_TPB + tid;
    if (i < e) {
      es[j] = src[i];
      ed[j] = dst[i];
      atomicAdd(&hist[ed[j] >> BKT_SHIFT], 1);
    } else {
      es[j] = -1; ed[j] = 0;
    }
  }
  __syncthreads();
  for (int b = tid; b < nbkt; b += FILL_TPB) {
    int cnt = hist[b];
    hist[b] = cnt ? atomicAdd(&bcur[b], cnt) : 0;
  }
  __syncthreads();
#pragma unroll
  for (int j = 0; j < FILL_EPT; ++j) {
    if (es[j] >= 0) {
      int b = ed[j] >> BKT_SHIFT;
      int p = atomicAdd(&hist[b], 1);
      if (p < BKT_CAP)
        bedges[(size_t)b * BKT_CAP + p] =
            (unsigned)es[j] | ((unsigned)(ed[j] & (BKT_NODES - 1)) << 17);
    }
  }
}

// ---------------- stage 2: in-LDS counting sort per bucket -> CSR ----------------
__global__ __launch_bounds__(256) void bucket_sort(
    const int* __restrict__ bcur, const unsigned* __restrict__ bedges,
    int* __restrict__ csr, int* __restrict__ row_beg, int* __restrict__ deg,
    int n) {
  __shared__ unsigned rec[BKT_CAP];
  __shared__ int srcs[BKT_CAP];
  __shared__ int hist[BKT_NODES];
  __shared__ int cursor[BKT_NODES];
  int tid = threadIdx.x;
  int b = blockIdx.x;
  int cnt = bcur[b];
  if (cnt > BKT_CAP) cnt = BKT_CAP;
  const unsigned* eb = bedges + (size_t)b * BKT_CAP;

  if (tid < BKT_NODES) hist[tid] = 0;
  __syncthreads();
  for (int i = tid; i < cnt; i += 256) {
    unsigned r = eb[i];
    rec[i] = r;
    atomicAdd(&hist[(r >> 17) & 127], 1);
  }
  __syncthreads();
  int myc = (tid < BKT_NODES) ? hist[tid] : 0;
#pragma unroll
  for (int off = 1; off < BKT_NODES; off <<= 1) {
    int v = 0;
    if (tid < BKT_NODES && tid >= off) v = hist[tid - off];
    __syncthreads();
    if (tid < BKT_NODES) hist[tid] += v;
    __syncthreads();
  }
  if (tid < BKT_NODES) {
    int start = hist[tid] - myc;
    cursor[tid] = start;
    int node = b * BKT_NODES + tid;
    if (node < n) {
      row_beg[node] = b * BKT_CAP + start;
      deg[node] = myc;
    }
  }
  __syncthreads();
  for (int i = tid; i < cnt; i += 256) {
    unsigned r = rec[i];
    int p = atomicAdd(&cursor[(r >> 17) & 127], 1);
    srcs[p] = (int)(r & 0x1FFFFu);
  }
  __syncthreads();
  for (int i = tid; i < cnt; i += 256)
    csr[(size_t)b * BKT_CAP + i] = srcs[i];
}

// ---------------- mean aggregation: one wave per node, 8-deep gather ----------------
__global__ __launch_bounds__(256) void agg_kernel(const unsigned* __restrict__ h,
                                                  const int* __restrict__ row_beg,
                                                  const int* __restrict__ deg,
                                                  const int* __restrict__ csr,
                                                  unsigned* __restrict__ mean, int n) {
  int node = (int)((blockIdx.x * blockDim.x + threadIdx.x) >> 6);
  if (node >= n) return;
  int lane = threadIdx.x & 63;
  int beg = row_beg[node], d = deg[node];
  float ax = 0.f, ay = 0.f;
  for (int j0 = 0; j0 < d; j0 += 64) {
    int cnt = min(64, d - j0);
    int li = j0 + (lane < cnt ? lane : cnt - 1);
    int sv = csr[beg + li];
    int j = 0;
    for (; j + 8 <= cnt; j += 8) {
      unsigned v[8];
#pragma unroll
      for (int q = 0; q < 8; ++q) {
        int s = __shfl(sv, j + q);
        v[q] = h[(size_t)s * (H / 2) + lane];
      }
#pragma unroll
      for (int q = 0; q < 8; ++q) {
        ax += bf2f(v[q] & 0xffffu);
        ay += bf2f(v[q] >> 16);
      }
    }
    for (; j < cnt; ++j) {
      int s = __shfl(sv, j);
      unsigned v = h[(size_t)s * (H / 2) + lane];
      ax += bf2f(v & 0xffffu);
      ay += bf2f(v >> 16);
    }
  }
  float invd = 1.f / (float)(d > 0 ? d : 1);
  mean[(size_t)node * (H / 2) + lane] =
      (unsigned)f2bf(ax * invd) | ((unsigned)f2bf(ay * invd) << 16);
}

// ---------------- weight preconvert: Wt[m][k] = bf16(W[k][m]) ----------------
__global__ __launch_bounds__(256) void prep_w(
    const float* __restrict__ w_in, const float* __restrict__ w_l1,
    const float* __restrict__ w_r1, const float* __restrict__ w_l2,
    const float* __restrict__ w_r2, const float* __restrict__ w_out,
    unsigned short* __restrict__ t_in, unsigned short* __restrict__ t_l1,
    unsigned short* __restrict__ t_r1, unsigned short* __restrict__ t_l2,
    unsigned short* __restrict__ t_r2, unsigned short* __restrict__ t_out) {
  int i = blockIdx.x * 256 + threadIdx.x;
  const float* s; unsigned short* d; int K, M, off;
  if (i < 32768)       { s = w_in;  d = t_in;  K = 256; M = 128; off = i; }
  else if (i < 49152)  { s = w_l1;  d = t_l1;  K = 128; M = 128; off = i - 32768; }
  else if (i < 65536)  { s = w_r1;  d = t_r1;  K = 128; M = 128; off = i - 49152; }
  else if (i < 81920)  { s = w_l2;  d = t_l2;  K = 128; M = 128; off = i - 65536; }
  else if (i < 98304)  { s = w_r2;  d = t_r2;  K = 128; M = 128; off = i - 81920; }
  else if (i < 106496) { s = w_out; d = t_out; K = 128; M = 64;  off = i - 98304; }
  else return;
  int m = off / K, k = off % K;
  d[off] = f2bf(s[(size_t)k * M + m]);
}

// ---------------- bf16 MFMA GEMM, hoisted A-prefetch, barrier-free k-loop ----------------
// 256 thr = 4 waves, 128 rows/block. All A-fragments for ALL phases are loaded
// into registers up front (16 independent global_load_dwordx4 per wave for the
// 2-phase bf16 case) -> one latency exposure per GEMM, hidden behind Bs staging.
template <int NPH, int KOFF2, int AK, int M, int EPI, bool AFP32, bool OUTF32>
__global__ __launch_bounds__(256) void gemm_mfma(
    const void* __restrict__ A1, const void* __restrict__ A2,
    const unsigned short* __restrict__ W1, const unsigned short* __restrict__ W2,
    const float* __restrict__ bias, const float* __restrict__ gamma,
    const float* __restrict__ beta, void* __restrict__ Cv, int n) {
  constexpr int KP = 136;            // 128 + 8 pad
  constexpr int NT = M / 16;
  __shared__ __align__(16) unsigned short Bs[M * KP];

  int tid = threadIdx.x, lane = tid & 63, wave = tid >> 6;
  int m16 = lane & 15, quad = lane >> 4;
  int row0 = blockIdx.x * 128;

  f32x4 acc[2][NT];
#pragma unroll
  for (int rt = 0; rt < 2; ++rt)
#pragma unroll
    for (int t = 0; t < NT; ++t) acc[rt][t] = (f32x4){0.f, 0.f, 0.f, 0.f};

  int rowa[2];
#pragma unroll
  for (int rt = 0; rt < 2; ++rt) {
    int r = row0 + wave * 32 + rt * 16 + m16;
    rowa[rt] = (r < n) ? r : (n - 1);
  }

  bf16x8 af[NPH][2][4];
  if constexpr (!AFP32) {
    // hoist ALL phases' A-fragment loads: 8*NPH independent 16B loads in flight
#pragma unroll
    for (int ph = 0; ph < NPH; ++ph) {
      const unsigned short* A = (const unsigned short*)(ph ? A2 : A1);
      const int koff = ph ? KOFF2 : 0;
#pragma unroll
      for (int rt = 0; rt < 2; ++rt)
#pragma unroll
        for (int kt = 0; kt < 4; ++kt)
          af[ph][rt][kt] = *(const bf16x8*)(A + (size_t)rowa[rt] * AK + koff +
                                            kt * 32 + quad * 8);
    }
  }

#pragma unroll
  for (int ph = 0; ph < NPH; ++ph) {
    const unsigned short* W = ph ? W2 : W1;
    const int koff = ph ? KOFF2 : 0;
    if (ph) __syncthreads();

    if constexpr (AFP32) {
      // hoist this phase's 8 fp32 row-chunk loads (2x float4 each), convert
      const float* A = (const float*)(ph ? A2 : A1);
      float4 raw[2][4][2];
#pragma unroll
      for (int rt = 0; rt < 2; ++rt)
#pragma unroll
        for (int kt = 0; kt < 4; ++kt) {
          const float* ap = A + (size_t)rowa[rt] * AK + koff + kt * 32 + quad * 8;
          raw[rt][kt][0] = *(const float4*)ap;
          raw[rt][kt][1] = *(const float4*)(ap + 4);
        }
#pragma unroll
      for (int rt = 0; rt < 2; ++rt)
#pragma unroll
        for (int kt = 0; kt < 4; ++kt) {
          union { bf16x8 v; unsigned u[4]; } p;
          float4 v0 = raw[rt][kt][0], v1 = raw[rt][kt][1];
          p.u[0] = (unsigned)f2bf(v0.x) | ((unsigned)f2bf(v0.y) << 16);
          p.u[1] = (unsigned)f2bf(v0.z) | ((unsigned)f2bf(v0.w) << 16);
          p.u[2] = (unsigned)f2bf(v1.x) | ((unsigned)f2bf(v1.y) << 16);
          p.u[3] = (unsigned)f2bf(v1.z) | ((unsigned)f2bf(v1.w) << 16);
          af[ph][rt][kt] = p.v;
        }
    }

    // stage Wt[M][koff..koff+127] -> Bs[M][136]
    for (int i = tid; i < M * 16; i += 256) {
      int r = i >> 4, c = i & 15;
      *(uint4*)&Bs[r * KP + c * 8] = *(const uint4*)&W[(size_t)r * AK + koff + c * 8];
    }
    __syncthreads();
#pragma unroll
    for (int kt = 0; kt < 4; ++kt) {
#pragma unroll
      for (int t = 0; t < NT; ++t) {
        bf16x8 bfr = *(const bf16x8*)&Bs[(t * 16 + m16) * KP + kt * 32 + quad * 8];
        acc[0][t] = __builtin_amdgcn_mfma_f32_16x16x32_bf16(af[ph][0][kt], bfr,
                                                            acc[0][t], 0, 0, 0);
        acc[1][t] = __builtin_amdgcn_mfma_f32_16x16x32_bf16(af[ph][1][kt], bfr,
                                                            acc[1][t], 0, 0, 0);
      }
    }
  }

  const float inv_std = rsqrtf(1.f + 1e-5f);
#pragma unroll
  for (int t = 0; t < NT; ++t) {
    int col = t * 16 + m16;
    float bv = bias[col];
    float sc = 1.f, bt2 = 0.f;
    if constexpr (EPI == EPI_BN) {
      sc = gamma[col] * inv_std;
      bt2 = beta[col];
    }
#pragma unroll
    for (int rt = 0; rt < 2; ++rt) {
#pragma unroll
      for (int r = 0; r < 4; ++r) {
        int row = row0 + wave * 32 + rt * 16 + quad * 4 + r;
        if (row < n) {
          float v = acc[rt][t][r] + bv;
          if constexpr (EPI == EPI_BN) v = fmaxf(v * sc + bt2, 0.f);
          else if constexpr (EPI == EPI_RELU) v = fmaxf(v, 0.f);
          if constexpr (OUTF32)
            ((float*)Cv)[(size_t)row * M + col] = v;
          else
            ((unsigned short*)Cv)[(size_t)row * M + col] = f2bf(v);
        }
      }
    }
  }
}

extern "C" void kernel_launch(void* const* d_in, const int* in_sizes, int n_in,
                              void* d_out, int out_size, void* d_ws, size_t ws_size,
                              hipStream_t stream) {
  const float* x     = (const float*)d_in[0];
  const int*   ei    = (const int*)d_in[1];
  const float* w_in  = (const float*)d_in[2];
  const float* b_in  = (const float*)d_in[3];
  const float* w_l1  = (const float*)d_in[4];
  const float* b_l1  = (const float*)d_in[5];
  const float* w_r1  = (const float*)d_in[6];
  const float* g1    = (const float*)d_in[7];
  const float* be1   = (const float*)d_in[8];
  const float* w_l2  = (const float*)d_in[9];
  const float* b_l2  = (const float*)d_in[10];
  const float* w_r2  = (const float*)d_in[11];
  const float* g2    = (const float*)d_in[12];
  const float* be2   = (const float*)d_in[13];
  const float* w_out = (const float*)d_in[14];
  const float* b_out = (const float*)d_in[15];
  float* out = (float*)d_out;

  int N = in_sizes[0] / DIN;
  int E = in_sizes[1] / 2;
  const int* src = ei;       // edge_index[0]
  const int* dst = ei + E;   // edge_index[1]
  int nbkt = (N + BKT_NODES - 1) / BKT_NODES;   // 782

  char* ws = (char*)d_ws;
  size_t off = 0;
  auto alloc = [&](size_t bytes) -> char* {
    char* p = ws + off;
    off += (bytes + 255) & ~(size_t)255;
    return p;
  };
  unsigned short* buf0 = (unsigned short*)alloc((size_t)N * H * 2);  // h0 -> mean2
  unsigned short* buf1 = (unsigned short*)alloc((size_t)N * H * 2);  // mean1 -> h2
  unsigned short* buf2 = (unsigned short*)alloc((size_t)N * H * 2);  // h1
  int* bcur        = (int*)alloc((size_t)nbkt * 4);
  unsigned* bedges = (unsigned*)alloc((size_t)nbkt * BKT_CAP * 4);
  int* csr         = (int*)alloc((size_t)nbkt * BKT_CAP * 4);
  int* row_beg     = (int*)alloc((size_t)N * 4);
  int* deg         = (int*)alloc((size_t)N * 4);
  unsigned short* t_in  = (unsigned short*)alloc(32768 * 2);
  unsigned short* t_l1  = (unsigned short*)alloc(16384 * 2);
  unsigned short* t_r1  = (unsigned short*)alloc(16384 * 2);
  unsigned short* t_l2  = (unsigned short*)alloc(16384 * 2);
  unsigned short* t_r2  = (unsigned short*)alloc(16384 * 2);
  unsigned short* t_out = (unsigned short*)alloc(8192 * 2);
  (void)ws_size;

  // ---- CSR build: bucket -> in-LDS counting sort ----
  hipMemsetAsync(bcur, 0, (size_t)nbkt * 4, stream);
  bucket_fill<<<(E + FILL_EPB - 1) / FILL_EPB, FILL_TPB, 0, stream>>>(
      src, dst, bcur, bedges, nbkt, E);
  bucket_sort<<<nbkt, 256, 0, stream>>>(bcur, bedges, csr, row_beg, deg, N);
  prep_w<<<(106496 + 255) / 256, 256, 0, stream>>>(
      w_in, w_l1, w_r1, w_l2, w_r2, w_out, t_in, t_l1, t_r1, t_l2, t_r2, t_out);

  int gblocks = (N + 127) / 128;
  int ablocks = (N + 3) / 4;

  // h0 = relu(x @ w_in + b_in)
  gemm_mfma<2, 128, 256, 128, EPI_RELU, true, false><<<gblocks, 256, 0, stream>>>(
      x, x, t_in, t_in, b_in, nullptr, nullptr, buf0, N);
  // mean1
  agg_kernel<<<ablocks, 256, 0, stream>>>((const unsigned*)buf0, row_beg, deg,
                                          csr, (unsigned*)buf1, N);
  // h1 = relu(bn(mean1@w_l1 + h0@w_r1 + b_l1))
  gemm_mfma<2, 0, 128, 128, EPI_BN, false, false><<<gblocks, 256, 0, stream>>>(
      buf1, buf0, t_l1, t_r1, b_l1, g1, be1, buf2, N);
  // mean2
  agg_kernel<<<ablocks, 256, 0, stream>>>((const unsigned*)buf2, row_beg, deg,
                                          csr, (unsigned*)buf0, N);
  // h2 = relu(bn(mean2@w_l2 + h1@w_r2 + b_l2))
  gemm_mfma<2, 0, 128, 128, EPI_BN, false, false><<<gblocks, 256, 0, stream>>>(
      buf0, buf2, t_l2, t_r2, b_l2, g2, be2, buf1, N);
  // out = h2 @ w_out + b_out
  gemm_mfma<1, 0, 128, 64, EPI_NONE, false, true><<<gblocks, 256, 0, stream>>>(
      buf1, buf1, t_out, t_out, b_out, nullptr, nullptr, out, N);
}

// Round 7
// 429.947 us; speedup vs baseline: 7.1809x; 1.0847x over previous
//
#include <hip/hip_runtime.h>

#define DIN 256
#define H   128
#define DOUT 64

#define EPI_RELU 0
#define EPI_BN   1
#define EPI_NONE 2

#define BKT_SHIFT 7                 // 128 nodes per bucket
#define BKT_NODES 128
#define BKT_CAP   4096              // slots per bucket (mean 2048, sigma ~45)

typedef __attribute__((ext_vector_type(8))) short bf16x8;
typedef __attribute__((ext_vector_type(4))) float f32x4;

__device__ inline unsigned short f2bf(float f) {
  union { float f; unsigned u; } v; v.f = f;
  unsigned u = v.u;
  u += 0x7FFFu + ((u >> 16) & 1u);   // round-to-nearest-even
  return (unsigned short)(u >> 16);
}
__device__ inline float bf2f(unsigned u16) {
  union { unsigned u; float f; } v; v.u = u16 << 16;
  return v.f;
}

// ---------------- stage 1: bucket edges by dst>>7 ----------------
#define FILL_TPB 1024
#define FILL_EPT 16
#define FILL_EPB (FILL_TPB * FILL_EPT)

__global__ __launch_bounds__(FILL_TPB) void bucket_fill(
    const int* __restrict__ src, const int* __restrict__ dst,
    int* __restrict__ bcur, unsigned* __restrict__ bedges,
    int nbkt, int e) {
  __shared__ int hist[1024];        // >= nbkt (782)
  int tid = threadIdx.x;
  int base = blockIdx.x * FILL_EPB;
  for (int i = tid; i < nbkt; i += FILL_TPB) hist[i] = 0;
  __syncthreads();

  int es[FILL_EPT], ed[FILL_EPT];
#pragma unroll
  for (int j = 0; j < FILL_EPT; ++j) {
    int i = base + j * FILL_TPB + tid;
    if (i < e) {
      es[j] = src[i];
      ed[j] = dst[i];
      atomicAdd(&hist[ed[j] >> BKT_SHIFT], 1);
    } else {
      es[j] = -1; ed[j] = 0;
    }
  }
  __syncthreads();
  for (int b = tid; b < nbkt; b += FILL_TPB) {
    int cnt = hist[b];
    hist[b] = cnt ? atomicAdd(&bcur[b], cnt) : 0;
  }
  __syncthreads();
#pragma unroll
  for (int j = 0; j < FILL_EPT; ++j) {
    if (es[j] >= 0) {
      int b = ed[j] >> BKT_SHIFT;
      int p = atomicAdd(&hist[b], 1);
      if (p < BKT_CAP)
        bedges[(size_t)b * BKT_CAP + p] =
            (unsigned)es[j] | ((unsigned)(ed[j] & (BKT_NODES - 1)) << 17);
    }
  }
}

// ---------------- stage 2: in-LDS counting sort per bucket -> CSR ----------------
__global__ __launch_bounds__(256) void bucket_sort(
    const int* __restrict__ bcur, const unsigned* __restrict__ bedges,
    int* __restrict__ csr, int* __restrict__ row_beg, int* __restrict__ deg,
    int n) {
  __shared__ unsigned rec[BKT_CAP];
  __shared__ int srcs[BKT_CAP];
  __shared__ int hist[BKT_NODES];
  __shared__ int cursor[BKT_NODES];
  int tid = threadIdx.x;
  int b = blockIdx.x;
  int cnt = bcur[b];
  if (cnt > BKT_CAP) cnt = BKT_CAP;
  const unsigned* eb = bedges + (size_t)b * BKT_CAP;

  if (tid < BKT_NODES) hist[tid] = 0;
  __syncthreads();
  for (int i = tid; i < cnt; i += 256) {
    unsigned r = eb[i];
    rec[i] = r;
    atomicAdd(&hist[(r >> 17) & 127], 1);
  }
  __syncthreads();
  int myc = (tid < BKT_NODES) ? hist[tid] : 0;
#pragma unroll
  for (int off = 1; off < BKT_NODES; off <<= 1) {
    int v = 0;
    if (tid < BKT_NODES && tid >= off) v = hist[tid - off];
    __syncthreads();
    if (tid < BKT_NODES) hist[tid] += v;
    __syncthreads();
  }
  if (tid < BKT_NODES) {
    int start = hist[tid] - myc;
    cursor[tid] = start;
    int node = b * BKT_NODES + tid;
    if (node < n) {
      row_beg[node] = b * BKT_CAP + start;
      deg[node] = myc;
    }
  }
  __syncthreads();
  for (int i = tid; i < cnt; i += 256) {
    unsigned r = rec[i];
    int p = atomicAdd(&cursor[(r >> 17) & 127], 1);
    srcs[p] = (int)(r & 0x1FFFFu);
  }
  __syncthreads();
  for (int i = tid; i < cnt; i += 256)
    csr[(size_t)b * BKT_CAP + i] = srcs[i];
}

// ---------------- mean aggregation: one wave per node, 8-deep gather ----------------
__global__ __launch_bounds__(256) void agg_kernel(const unsigned* __restrict__ h,
                                                  const int* __restrict__ row_beg,
                                                  const int* __restrict__ deg,
                                                  const int* __restrict__ csr,
                                                  unsigned* __restrict__ mean, int n) {
  int node = (int)((blockIdx.x * blockDim.x + threadIdx.x) >> 6);
  if (node >= n) return;
  int lane = threadIdx.x & 63;
  int beg = row_beg[node], d = deg[node];
  float ax = 0.f, ay = 0.f;
  for (int j0 = 0; j0 < d; j0 += 64) {
    int cnt = min(64, d - j0);
    int li = j0 + (lane < cnt ? lane : cnt - 1);
    int sv = csr[beg + li];
    int j = 0;
    for (; j + 8 <= cnt; j += 8) {
      unsigned v[8];
#pragma unroll
      for (int q = 0; q < 8; ++q) {
        int s = __shfl(sv, j + q);
        v[q] = h[(size_t)s * (H / 2) + lane];
      }
#pragma unroll
      for (int q = 0; q < 8; ++q) {
        ax += bf2f(v[q] & 0xffffu);
        ay += bf2f(v[q] >> 16);
      }
    }
    for (; j < cnt; ++j) {
      int s = __shfl(sv, j);
      unsigned v = h[(size_t)s * (H / 2) + lane];
      ax += bf2f(v & 0xffffu);
      ay += bf2f(v >> 16);
    }
  }
  float invd = 1.f / (float)(d > 0 ? d : 1);
  mean[(size_t)node * (H / 2) + lane] =
      (unsigned)f2bf(ax * invd) | ((unsigned)f2bf(ay * invd) << 16);
}

// ---------------- weight preconvert: Wt[m][k] = bf16(W[k][m]) ----------------
__global__ __launch_bounds__(256) void prep_w(
    const float* __restrict__ w_in, const float* __restrict__ w_l1,
    const float* __restrict__ w_r1, const float* __restrict__ w_l2,
    const float* __restrict__ w_r2, const float* __restrict__ w_out,
    unsigned short* __restrict__ t_in, unsigned short* __restrict__ t_l1,
    unsigned short* __restrict__ t_r1, unsigned short* __restrict__ t_l2,
    unsigned short* __restrict__ t_r2, unsigned short* __restrict__ t_out) {
  int i = blockIdx.x * 256 + threadIdx.x;
  const float* s; unsigned short* d; int K, M, off;
  if (i < 32768)       { s = w_in;  d = t_in;  K = 256; M = 128; off = i; }
  else if (i < 49152)  { s = w_l1;  d = t_l1;  K = 128; M = 128; off = i - 32768; }
  else if (i < 65536)  { s = w_r1;  d = t_r1;  K = 128; M = 128; off = i - 49152; }
  else if (i < 81920)  { s = w_l2;  d = t_l2;  K = 128; M = 128; off = i - 65536; }
  else if (i < 98304)  { s = w_r2;  d = t_r2;  K = 128; M = 128; off = i - 81920; }
  else if (i < 106496) { s = w_out; d = t_out; K = 128; M = 64;  off = i - 98304; }
  else return;
  int m = off / K, k = off % K;
  d[off] = f2bf(s[(size_t)k * M + m]);
}

// ---------------- bf16 MFMA GEMM v3: wave-contiguous loads + swizzled LDS ----------------
// 64 rows/block, 256 thr = 4 waves (wave w owns rows w*16..+15). All global
// loads are 1KB-contiguous per wave-instruction (lane i -> base + i*16B).
// A and B tiles live in LDS with XOR swizzle on 16B chunks:
//   chunk' = (chunk + row) & 15  ->  every ds_read_b128 in the k-loop is
// exactly 2-way bank-aliased (free, m136), no padding (keeps b128 alignment).
template <int NPH, int KOFF2, int AKA, int AKW, int M, int EPI, bool AFP32, bool OUTF32>
__global__ __launch_bounds__(256) void gemm_mfma(
    const void* __restrict__ A1, const void* __restrict__ A2,
    const unsigned short* __restrict__ W1, const unsigned short* __restrict__ W2,
    const float* __restrict__ bias, const float* __restrict__ gamma,
    const float* __restrict__ beta, void* __restrict__ Cv, int n) {
  constexpr int NT = M / 16;
  __shared__ __align__(16) unsigned short As[64 * 128];   // 16 KB
  __shared__ __align__(16) unsigned short Bs[M * 128];    // 32/16 KB

  int tid = threadIdx.x, lane = tid & 63, wave = tid >> 6;
  int m16 = lane & 15, quad = lane >> 4;
  int row0 = blockIdx.x * 64;
  int sr = lane >> 4;          // row-in-group 0..3
  int sc = lane & 15;          // 16B chunk 0..15

  f32x4 acc[NT];
#pragma unroll
  for (int t = 0; t < NT; ++t) acc[t] = (f32x4){0.f, 0.f, 0.f, 0.f};

#pragma unroll
  for (int ph = 0; ph < NPH; ++ph) {
    const void* A_ = ph ? A2 : A1;
    const unsigned short* W = ph ? W2 : W1;
    const int koff = ph ? KOFF2 : 0;
    if (ph) __syncthreads();   // waves done reading previous tiles

    // ---- stage A tile: wave w rows w*16..+15 ----
    if constexpr (!AFP32) {
#pragma unroll
      for (int g = 0; g < 4; ++g) {
        int lr = wave * 16 + g * 4 + sr;
        int grow = row0 + lr; if (grow >= n) grow = n - 1;
        uint4 v = *(const uint4*)((const unsigned short*)A_ +
                                  (size_t)grow * AKA + koff + sc * 8);
        *(uint4*)&As[lr * 128 + ((sc + lr) & 15) * 8] = v;
      }
    } else {
      int sr2 = lane >> 5;     // 0..1
      int c32 = lane & 31;     // fp32 16B chunk 0..31
#pragma unroll
      for (int g = 0; g < 8; ++g) {
        int lr = wave * 16 + g * 2 + sr2;
        int grow = row0 + lr; if (grow >= n) grow = n - 1;
        float4 v = *(const float4*)((const float*)A_ +
                                    (size_t)grow * AKA + koff + c32 * 4);
        unsigned p0 = (unsigned)f2bf(v.x) | ((unsigned)f2bf(v.y) << 16);
        unsigned p1 = (unsigned)f2bf(v.z) | ((unsigned)f2bf(v.w) << 16);
        int ch = c32 >> 1;
        *(uint2*)&As[lr * 128 + ((ch + lr) & 15) * 8 + (c32 & 1) * 4] =
            make_uint2(p0, p1);
      }
    }
    // ---- stage B tile: wave w rows w*(M/4)..+M/4-1 ----
#pragma unroll
    for (int g = 0; g < M / 16; ++g) {
      int br = wave * (M / 4) + g * 4 + sr;
      uint4 v = *(const uint4*)(W + (size_t)br * AKW + koff + sc * 8);
      *(uint4*)&Bs[br * 128 + ((sc + br) & 15) * 8] = v;
    }
    __syncthreads();

    // ---- k-loop: LDS only ----
    int lrme = wave * 16 + m16;
#pragma unroll
    for (int kt = 0; kt < 4; ++kt) {
      int ch = kt * 4 + quad;
      bf16x8 a = *(const bf16x8*)&As[lrme * 128 + ((ch + lrme) & 15) * 8];
#pragma unroll
      for (int t = 0; t < NT; ++t) {
        int brow = t * 16 + m16;
        bf16x8 b = *(const bf16x8*)&Bs[brow * 128 + ((ch + brow) & 15) * 8];
        acc[t] = __builtin_amdgcn_mfma_f32_16x16x32_bf16(a, b, acc[t], 0, 0, 0);
      }
    }
  }

  const float inv_std = rsqrtf(1.f + 1e-5f);
#pragma unroll
  for (int t = 0; t < NT; ++t) {
    int col = t * 16 + m16;
    float bv = bias[col];
    float sc2 = 1.f, bt2 = 0.f;
    if constexpr (EPI == EPI_BN) {
      sc2 = gamma[col] * inv_std;
      bt2 = beta[col];
    }
#pragma unroll
    for (int r = 0; r < 4; ++r) {
      int row = row0 + wave * 16 + quad * 4 + r;
      if (row < n) {
        float v = acc[t][r] + bv;
        if constexpr (EPI == EPI_BN) v = fmaxf(v * sc2 + bt2, 0.f);
        else if constexpr (EPI == EPI_RELU) v = fmaxf(v, 0.f);
        if constexpr (OUTF32)
          ((float*)Cv)[(size_t)row * M + col] = v;
        else
          ((unsigned short*)Cv)[(size_t)row * M + col] = f2bf(v);
      }
    }
  }
}

extern "C" void kernel_launch(void* const* d_in, const int* in_sizes, int n_in,
                              void* d_out, int out_size, void* d_ws, size_t ws_size,
                              hipStream_t stream) {
  const float* x     = (const float*)d_in[0];
  const int*   ei    = (const int*)d_in[1];
  const float* w_in  = (const float*)d_in[2];
  const float* b_in  = (const float*)d_in[3];
  const float* w_l1  = (const float*)d_in[4];
  const float* b_l1  = (const float*)d_in[5];
  const float* w_r1  = (const float*)d_in[6];
  const float* g1    = (const float*)d_in[7];
  const float* be1   = (const float*)d_in[8];
  const float* w_l2  = (const float*)d_in[9];
  const float* b_l2  = (const float*)d_in[10];
  const float* w_r2  = (const float*)d_in[11];
  const float* g2    = (const float*)d_in[12];
  const float* be2   = (const float*)d_in[13];
  const float* w_out = (const float*)d_in[14];
  const float* b_out = (const float*)d_in[15];
  float* out = (float*)d_out;

  int N = in_sizes[0] / DIN;
  int E = in_sizes[1] / 2;
  const int* src = ei;       // edge_index[0]
  const int* dst = ei + E;   // edge_index[1]
  int nbkt = (N + BKT_NODES - 1) / BKT_NODES;   // 782

  char* ws = (char*)d_ws;
  size_t off = 0;
  auto alloc = [&](size_t bytes) -> char* {
    char* p = ws + off;
    off += (bytes + 255) & ~(size_t)255;
    return p;
  };
  unsigned short* buf0 = (unsigned short*)alloc((size_t)N * H * 2);  // h0 -> mean2
  unsigned short* buf1 = (unsigned short*)alloc((size_t)N * H * 2);  // mean1 -> h2
  unsigned short* buf2 = (unsigned short*)alloc((size_t)N * H * 2);  // h1
  int* bcur        = (int*)alloc((size_t)nbkt * 4);
  unsigned* bedges = (unsigned*)alloc((size_t)nbkt * BKT_CAP * 4);
  int* csr         = (int*)alloc((size_t)nbkt * BKT_CAP * 4);
  int* row_beg     = (int*)alloc((size_t)N * 4);
  int* deg         = (int*)alloc((size_t)N * 4);
  unsigned short* t_in  = (unsigned short*)alloc(32768 * 2);
  unsigned short* t_l1  = (unsigned short*)alloc(16384 * 2);
  unsigned short* t_r1  = (unsigned short*)alloc(16384 * 2);
  unsigned short* t_l2  = (unsigned short*)alloc(16384 * 2);
  unsigned short* t_r2  = (unsigned short*)alloc(16384 * 2);
  unsigned short* t_out = (unsigned short*)alloc(8192 * 2);
  (void)ws_size;

  // ---- CSR build: bucket -> in-LDS counting sort ----
  hipMemsetAsync(bcur, 0, (size_t)nbkt * 4, stream);
  bucket_fill<<<(E + FILL_EPB - 1) / FILL_EPB, FILL_TPB, 0, stream>>>(
      src, dst, bcur, bedges, nbkt, E);
  bucket_sort<<<nbkt, 256, 0, stream>>>(bcur, bedges, csr, row_beg, deg, N);
  prep_w<<<(106496 + 255) / 256, 256, 0, stream>>>(
      w_in, w_l1, w_r1, w_l2, w_r2, w_out, t_in, t_l1, t_r1, t_l2, t_r2, t_out);

  int gblocks = (N + 63) / 64;   // 1563
  int ablocks = (N + 3) / 4;

  // h0 = relu(x @ w_in + b_in)       [fp32 A, K=256 via 2 phases of same x]
  gemm_mfma<2, 128, 256, 256, 128, EPI_RELU, true, false><<<gblocks, 256, 0, stream>>>(
      x, x, t_in, t_in, b_in, nullptr, nullptr, buf0, N);
  // mean1
  agg_kernel<<<ablocks, 256, 0, stream>>>((const unsigned*)buf0, row_beg, deg,
                                          csr, (unsigned*)buf1, N);
  // h1 = relu(bn(mean1@w_l1 + h0@w_r1 + b_l1))
  gemm_mfma<2, 0, 128, 128, 128, EPI_BN, false, false><<<gblocks, 256, 0, stream>>>(
      buf1, buf0, t_l1, t_r1, b_l1, g1, be1, buf2, N);
  // mean2
  agg_kernel<<<ablocks, 256, 0, stream>>>((const unsigned*)buf2, row_beg, deg,
                                          csr, (unsigned*)buf0, N);
  // h2 = relu(bn(mean2@w_l2 + h1@w_r2 + b_l2))
  gemm_mfma<2, 0, 128, 128, 128, EPI_BN, false, false><<<gblocks, 256, 0, stream>>>(
      buf0, buf2, t_l2, t_r2, b_l2, g2, be2, buf1, N);
  // out = h2 @ w_out + b_out
  gemm_mfma<1, 0, 128, 128, 64, EPI_NONE, false, true><<<gblocks, 256, 0, stream>>>(
      buf1, buf1, t_out, t_out, b_out, nullptr, nullptr, out, N);
}